// Round 1
// baseline (291.726 us; speedup 1.0000x reference)
//
#include <hip/hip_runtime.h>
#include <hip/hip_bf16.h>
#include <stdint.h>

// Problem constants
#define MD     128      // M_DIM
#define W4     50625    // 15^4 windows per batch
#define ROWS   202500   // 4 * W4 GEMM rows
#define LBAS   256      // basis count
#define POOL_THREADS 216000   // 4*15^3 strips * 16 i-groups
#define NK_OFF 51840000       // byte offset of Nk table in ws (after bf16 pooled)

typedef __attribute__((ext_vector_type(8))) __bf16 bf16x8;
typedef __attribute__((ext_vector_type(4))) float floatx4;
typedef __attribute__((ext_vector_type(8))) unsigned short ushortx8;

__device__ __forceinline__ float bf2f(unsigned short u){
  union { unsigned int i; float f; } v; v.i = ((unsigned int)u) << 16; return v.f;
}
__device__ __forceinline__ unsigned short f2bf(float x){
  union { float f; unsigned int i; } v; v.f = x;
  unsigned int r = v.i + 0x7FFFu + ((v.i >> 16) & 1u);
  return (unsigned short)(r >> 16);
}
// Bbasis[0,0] == cos(pi)^4 == 1.0f exactly. fp32 -> first dword 0x3F800000.
// bf16 -> dword is (Bbasis[0,1]=0.0625 -> 0x3D80)<<16 | 0x3F80 = 0x3D803F80.
__device__ __forceinline__ int detect_f32(const void* Bbasis){
  return ((const unsigned int*)Bbasis)[0] == 0x3F800000u;
}

// ---------------- K0: Nk table (256 x 128 fp32) ----------------
__global__ __launch_bounds__(256) void nk_kernel(const void* __restrict__ Acoeff,
                                                 const void* __restrict__ Bbasis,
                                                 float* __restrict__ NkFull){
  int gid = blockIdx.x * 256 + threadIdx.x;
  if (gid >= LBAS * MD) return;
  int idx = gid >> 7;   // 0..255
  int j   = gid & 127;
  float a, b;
  if (detect_f32(Bbasis)){
    a = ((const float*)Acoeff)[j * LBAS + idx];
    b = ((const float*)Bbasis)[idx * MD + j];
  } else {
    a = bf2f(((const unsigned short*)Acoeff)[j * LBAS + idx]);
    b = bf2f(((const unsigned short*)Bbasis)[idx * MD + j]);
  }
  NkFull[gid] = a * b;   // gid == idx*128 + j
}

// ---------------- K1: 2^4 window-mean -> pooled (bf16, row-major 202500x128) ----------------
template<int ISF32>
__device__ __forceinline__ void pool_body(const void* __restrict__ vec,
                                          unsigned short* __restrict__ pooled,
                                          int gid){
  const int ig = gid & 15;                 // i-group: 8 channels each
  unsigned int strip = (unsigned int)(gid >> 4);   // (b,w1,w2,w3)
  const unsigned int w3 = strip % 15u; strip /= 15u;
  const unsigned int w2 = strip % 15u; strip /= 15u;
  const unsigned int w1 = strip % 15u;
  const unsigned int b  = strip / 15u;
  // vec strides (elems): b 8388608, x1 524288, x2 32768, x3 2048, x4 128, i 1
  const unsigned int base = b*8388608u + w1*524288u + w2*32768u + w3*2048u
                          + (unsigned int)(ig * 8);
  unsigned int offs[8];
#pragma unroll
  for (int d = 0; d < 8; ++d){
    const unsigned int d1 = (d>>2)&1u, d2 = (d>>1)&1u, d3 = d&1u;
    offs[d] = base + d1*524288u + d2*32768u + d3*2048u;
  }
  const size_t prow0 = (size_t)b*50625u + w1*3375u + w2*225u + w3*15u;
  float prev[8], cur[8];
#pragma unroll 4
  for (int k4 = 0; k4 < 16; ++k4){
#pragma unroll
    for (int e = 0; e < 8; ++e) cur[e] = 0.f;
#pragma unroll
    for (int d = 0; d < 8; ++d){
      const unsigned int off = offs[d] + ((unsigned int)k4 << 7);
      if (ISF32){
        const float* vf = (const float*)vec;
        floatx4 lo = *(const floatx4*)(vf + off);
        floatx4 hi = *(const floatx4*)(vf + off + 4);
#pragma unroll
        for (int e = 0; e < 4; ++e){ cur[e] += lo[e]; cur[4+e] += hi[e]; }
      } else {
        const ushortx8 u = *(const ushortx8*)((const unsigned short*)vec + off);
#pragma unroll
        for (int e = 0; e < 8; ++e) cur[e] += bf2f(u[e]);
      }
    }
    if (k4 > 0){
      ushortx8 ov;
#pragma unroll
      for (int e = 0; e < 8; ++e) ov[e] = f2bf((prev[e] + cur[e]) * 0.0625f);
      *(ushortx8*)(pooled + (prow0 + (unsigned)(k4 - 1)) * 128 + ig * 8) = ov;
    }
#pragma unroll
    for (int e = 0; e < 8; ++e) prev[e] = cur[e];
  }
}

__global__ __launch_bounds__(256) void pool_kernel(const void* __restrict__ vec,
                                                   const void* __restrict__ Bbasis,
                                                   unsigned short* __restrict__ pooled){
  int gid = blockIdx.x * 256 + threadIdx.x;
  if (gid >= POOL_THREADS) return;
  if (detect_f32(Bbasis)) pool_body<1>(vec, pooled, gid);
  else                    pool_body<0>(vec, pooled, gid);
}

// ---------------- K2: out[p,j] = Nk[idx(p),j] - sum_i pooled[p,i]*M[j,i] ----------------
__global__ __launch_bounds__(256) void gemm_kernel(const unsigned short* __restrict__ pooled,
                                                   const void* __restrict__ Mmat,
                                                   const float* __restrict__ NkFull,
                                                   const void* __restrict__ Bbasis,
                                                   void* __restrict__ out){
  // +8 shorts row padding: 272 B rows -> 4-bank rotation, <=2-way conflicts (free)
  __shared__ __align__(16) unsigned short sA[128][136];
  __shared__ __align__(16) unsigned short sB[128][136];
  __shared__ int sIdx[128];

  const int tid = threadIdx.x;
  const int p0  = blockIdx.x * 128;
  const int isF32 = detect_f32(Bbasis);

  {
    const int rr  = tid >> 4;    // 0..15
    const int l16 = tid & 15;
    // stage A: pooled rows p0..p0+127 (always bf16)
#pragma unroll
    for (int r8 = 0; r8 < 8; ++r8){
      const int row = r8 * 16 + rr;
      *(ushortx8*)&sA[row][l16 * 8] =
          *(const ushortx8*)(pooled + (size_t)(p0 + row) * 128 + l16 * 8);
    }
    // stage B: M (row-major j,i) converted to bf16
    if (isF32){
      const float* mf = (const float*)Mmat;
#pragma unroll
      for (int r8 = 0; r8 < 8; ++r8){
        const int row = r8 * 16 + rr;
        const float* src = mf + row * 128 + l16 * 8;
        floatx4 lo = *(const floatx4*)src;
        floatx4 hi = *(const floatx4*)(src + 4);
        ushortx8 v;
#pragma unroll
        for (int e = 0; e < 4; ++e){ v[e] = f2bf(lo[e]); v[4+e] = f2bf(hi[e]); }
        *(ushortx8*)&sB[row][l16 * 8] = v;
      }
    } else {
      const unsigned short* mh = (const unsigned short*)Mmat;
#pragma unroll
      for (int r8 = 0; r8 < 8; ++r8){
        const int row = r8 * 16 + rr;
        *(ushortx8*)&sB[row][l16 * 8] = *(const ushortx8*)(mh + row * 128 + l16 * 8);
      }
    }
  }
  if (tid < 128){
    const int p = p0 + tid;
    unsigned int w = (p < ROWS) ? (unsigned int)(p % W4) : 0u;
    const unsigned int w4 = w % 15u; w /= 15u;
    const unsigned int w3 = w % 15u; w /= 15u;
    const unsigned int w2 = w % 15u;
    const unsigned int w1 = w / 15u;
    sIdx[tid] = (int)(((w1 & 3u) << 6) | ((w2 & 3u) << 4) | ((w3 & 3u) << 2) | (w4 & 3u));
  }
  __syncthreads();

  const int wave = tid >> 6;     // 0..3 -> rows [wave*32, wave*32+32)
  const int lane = tid & 63;
  const int quad = lane >> 4;
  const int l16  = lane & 15;

  floatx4 acc[2][8];
#pragma unroll
  for (int rt = 0; rt < 2; ++rt)
#pragma unroll
    for (int c = 0; c < 8; ++c) acc[rt][c] = (floatx4){0.f, 0.f, 0.f, 0.f};

#pragma unroll
  for (int s = 0; s < 4; ++s){
    bf16x8 af[2];
#pragma unroll
    for (int rt = 0; rt < 2; ++rt)
      af[rt] = *(const bf16x8*)&sA[wave * 32 + rt * 16 + l16][s * 32 + quad * 8];
#pragma unroll
    for (int c = 0; c < 8; ++c){
      const bf16x8 bfv = *(const bf16x8*)&sB[c * 16 + l16][s * 32 + quad * 8];
      acc[0][c] = __builtin_amdgcn_mfma_f32_16x16x32_bf16(af[0], bfv, acc[0][c], 0, 0, 0);
      acc[1][c] = __builtin_amdgcn_mfma_f32_16x16x32_bf16(af[1], bfv, acc[1][c], 0, 0, 0);
    }
  }

  // epilogue: C/D layout col=lane&15, row=quad*4+reg
#pragma unroll
  for (int rt = 0; rt < 2; ++rt){
#pragma unroll
    for (int reg = 0; reg < 4; ++reg){
      const int r = wave * 32 + rt * 16 + quad * 4 + reg;
      const int p = p0 + r;
      if (p < ROWS){
        const float* nkp = NkFull + (sIdx[r] << 7);
        if (isF32){
          float* op = (float*)out + (size_t)p * 128;
#pragma unroll
          for (int c = 0; c < 8; ++c){
            const int j = c * 16 + l16;
            op[j] = nkp[j] - acc[rt][c][reg];
          }
        } else {
          unsigned short* op = (unsigned short*)out + (size_t)p * 128;
#pragma unroll
          for (int c = 0; c < 8; ++c){
            const int j = c * 16 + l16;
            op[j] = f2bf(nkp[j] - acc[rt][c][reg]);
          }
        }
      }
    }
  }
}

extern "C" void kernel_launch(void* const* d_in, const int* in_sizes, int n_in,
                              void* d_out, int out_size, void* d_ws, size_t ws_size,
                              hipStream_t stream) {
  const void* vec = d_in[0];   // (4,16,16,16,16,128)
  const void* Mm  = d_in[1];   // (128,128)
  const void* Ac  = d_in[2];   // (128,256)
  const void* Bb  = d_in[3];   // (256,128)

  unsigned short* pooled = (unsigned short*)d_ws;                 // 202500*128 bf16 = 51.84 MB
  float* NkFull = (float*)((char*)d_ws + NK_OFF);                 // 256*128 fp32 = 128 KB

  nk_kernel<<<128, 256, 0, stream>>>(Ac, Bb, NkFull);
  pool_kernel<<<(POOL_THREADS + 255) / 256, 256, 0, stream>>>(vec, Bb, pooled);
  gemm_kernel<<<(ROWS + 127) / 128, 256, 0, stream>>>(pooled, Mm, NkFull, Bb, d_out);
}

// Round 2
// 283.898 us; speedup vs baseline: 1.0276x; 1.0276x over previous
//
#include <hip/hip_runtime.h>
#include <hip/hip_bf16.h>
#include <stdint.h>

// Problem constants
#define MD     128      // M_DIM
#define W4     50625    // 15^4 windows per batch
#define ROWS   202500   // 4 * W4 GEMM rows
#define LBAS   256      // basis count
#define POOL_THREADS 432000   // 4*15^3 strips(b,w2,w3,w4) * 32 i-groups of 4ch
#define NK_OFF 51840000       // byte offset of Nk table in ws (after bf16 pooled)

typedef __attribute__((ext_vector_type(8))) __bf16 bf16x8;
typedef __attribute__((ext_vector_type(4))) float floatx4;
typedef __attribute__((ext_vector_type(8))) unsigned short ushortx8;
typedef __attribute__((ext_vector_type(4))) unsigned short ushortx4;

__device__ __forceinline__ float bf2f(unsigned short u){
  union { unsigned int i; float f; } v; v.i = ((unsigned int)u) << 16; return v.f;
}
__device__ __forceinline__ unsigned short f2bf(float x){
  union { float f; unsigned int i; } v; v.f = x;
  unsigned int r = v.i + 0x7FFFu + ((v.i >> 16) & 1u);
  return (unsigned short)(r >> 16);
}
// Bbasis[0,0] == cos(pi)^4 == 1.0f exactly. fp32 -> first dword 0x3F800000.
__device__ __forceinline__ int detect_f32(const void* Bbasis){
  return ((const unsigned int*)Bbasis)[0] == 0x3F800000u;
}

// ---------------- K0: Nk table (256 x 128 fp32) ----------------
__global__ __launch_bounds__(256) void nk_kernel(const void* __restrict__ Acoeff,
                                                 const void* __restrict__ Bbasis,
                                                 float* __restrict__ NkFull){
  int gid = blockIdx.x * 256 + threadIdx.x;
  if (gid >= LBAS * MD) return;
  int idx = gid >> 7;   // 0..255
  int j   = gid & 127;
  float a, b;
  if (detect_f32(Bbasis)){
    a = ((const float*)Acoeff)[j * LBAS + idx];
    b = ((const float*)Bbasis)[idx * MD + j];
  } else {
    a = bf2f(((const unsigned short*)Acoeff)[j * LBAS + idx]);
    b = bf2f(((const unsigned short*)Bbasis)[idx * MD + j]);
  }
  NkFull[gid] = a * b;   // gid == idx*128 + j
}

// ---------------- K1: 2^4 window-mean -> pooled (bf16, row-major 202500x128) ----
// Running-sum along DIM 1 (the 2 MB-stride dim): its x2 re-read stays in
// registers; dims 2/3/4 overlap (<=128 KB reach) is left to L1/L2.
template<int ISF32>
__device__ __forceinline__ void pool_body(const void* __restrict__ vec,
                                          unsigned short* __restrict__ pooled,
                                          int gid){
  const int ig = gid & 31;                        // 4 channels each
  unsigned int strip = (unsigned int)(gid >> 5);  // (b,w2,w3,w4)
  const unsigned int w4 = strip % 15u; strip /= 15u;
  const unsigned int w3 = strip % 15u; strip /= 15u;
  const unsigned int w2 = strip % 15u;
  const unsigned int b  = strip / 15u;
  // vec strides (elems): b 8388608, x1 524288, x2 32768, x3 2048, x4 128, i 1
  const unsigned int base = b*8388608u + w2*32768u + w3*2048u + w4*128u
                          + (unsigned int)(ig * 4);
  unsigned int offs[8];
#pragma unroll
  for (int d = 0; d < 8; ++d){
    const unsigned int d2 = (d>>2)&1u, d3 = (d>>1)&1u, d4 = d&1u;
    offs[d] = base + d2*32768u + d3*2048u + d4*128u;
  }
  const unsigned int prowB = b*50625u + w2*225u + w3*15u + w4;  // + w1*3375
  float prev[4], cur[4];
#pragma unroll 4
  for (int k1 = 0; k1 < 16; ++k1){
#pragma unroll
    for (int e = 0; e < 4; ++e) cur[e] = 0.f;
#pragma unroll
    for (int d = 0; d < 8; ++d){
      const unsigned int off = offs[d] + (unsigned int)k1 * 524288u;
      if (ISF32){
        const floatx4 v = *(const floatx4*)((const float*)vec + off);
#pragma unroll
        for (int e = 0; e < 4; ++e) cur[e] += v[e];
      } else {
        const ushortx4 u = *(const ushortx4*)((const unsigned short*)vec + off);
#pragma unroll
        for (int e = 0; e < 4; ++e) cur[e] += bf2f(u[e]);
      }
    }
    if (k1 > 0){
      ushortx4 ov;
#pragma unroll
      for (int e = 0; e < 4; ++e) ov[e] = f2bf((prev[e] + cur[e]) * 0.0625f);
      *(ushortx4*)(pooled + (size_t)(prowB + (unsigned)(k1 - 1) * 3375u) * 128 + ig * 4) = ov;
    }
#pragma unroll
    for (int e = 0; e < 4; ++e) prev[e] = cur[e];
  }
}

__global__ __launch_bounds__(256) void pool_kernel(const void* __restrict__ vec,
                                                   const void* __restrict__ Bbasis,
                                                   unsigned short* __restrict__ pooled){
  int gid = blockIdx.x * 256 + threadIdx.x;
  if (gid >= POOL_THREADS) return;
  if (detect_f32(Bbasis)) pool_body<1>(vec, pooled, gid);
  else                    pool_body<0>(vec, pooled, gid);
}

// ---------------- K2: out[p,j] = Nk[idx(p),j] - sum_i pooled[p,i]*M[j,i] ----------------
union GemmSmem {
  struct { unsigned short A[128][136]; unsigned short B[128][136]; } ab; // 69632 B
  float C[128][132];                                                     // 67584 B
};

__global__ __launch_bounds__(256) void gemm_kernel(const unsigned short* __restrict__ pooled,
                                                   const void* __restrict__ Mmat,
                                                   const float* __restrict__ NkFull,
                                                   const void* __restrict__ Bbasis,
                                                   void* __restrict__ out){
  __shared__ __align__(16) GemmSmem sm;
  __shared__ int sIdx[128];

  const int tid = threadIdx.x;
  const int p0  = blockIdx.x * 128;
  const int isF32 = detect_f32(Bbasis);

  {
    const int rr  = tid >> 4;    // 0..15
    const int l16 = tid & 15;
    // stage A: pooled rows p0..p0+127 (always bf16)
#pragma unroll
    for (int r8 = 0; r8 < 8; ++r8){
      const int row = r8 * 16 + rr;
      *(ushortx8*)&sm.ab.A[row][l16 * 8] =
          *(const ushortx8*)(pooled + (size_t)(p0 + row) * 128 + l16 * 8);
    }
    // stage B: M (row-major j,i) converted to bf16
    if (isF32){
      const float* mf = (const float*)Mmat;
#pragma unroll
      for (int r8 = 0; r8 < 8; ++r8){
        const int row = r8 * 16 + rr;
        const float* src = mf + row * 128 + l16 * 8;
        floatx4 lo = *(const floatx4*)src;
        floatx4 hi = *(const floatx4*)(src + 4);
        ushortx8 v;
#pragma unroll
        for (int e = 0; e < 4; ++e){ v[e] = f2bf(lo[e]); v[4+e] = f2bf(hi[e]); }
        *(ushortx8*)&sm.ab.B[row][l16 * 8] = v;
      }
    } else {
      const unsigned short* mh = (const unsigned short*)Mmat;
#pragma unroll
      for (int r8 = 0; r8 < 8; ++r8){
        const int row = r8 * 16 + rr;
        *(ushortx8*)&sm.ab.B[row][l16 * 8] = *(const ushortx8*)(mh + row * 128 + l16 * 8);
      }
    }
  }
  if (tid < 128){
    const int p = p0 + tid;
    unsigned int w = (p < ROWS) ? (unsigned int)(p % W4) : 0u;
    const unsigned int w4 = w % 15u; w /= 15u;
    const unsigned int w3 = w % 15u; w /= 15u;
    const unsigned int w2 = w % 15u;
    const unsigned int w1 = w / 15u;
    sIdx[tid] = (int)(((w1 & 3u) << 6) | ((w2 & 3u) << 4) | ((w3 & 3u) << 2) | (w4 & 3u));
  }
  __syncthreads();

  const int wave = tid >> 6;     // 0..3 -> rows [wave*32, wave*32+32)
  const int lane = tid & 63;
  const int quad = lane >> 4;
  const int l16  = lane & 15;

  floatx4 acc[2][8];
#pragma unroll
  for (int rt = 0; rt < 2; ++rt)
#pragma unroll
    for (int c = 0; c < 8; ++c) acc[rt][c] = (floatx4){0.f, 0.f, 0.f, 0.f};

#pragma unroll
  for (int s = 0; s < 4; ++s){
    bf16x8 af[2];
#pragma unroll
    for (int rt = 0; rt < 2; ++rt)
      af[rt] = *(const bf16x8*)&sm.ab.A[wave * 32 + rt * 16 + l16][s * 32 + quad * 8];
#pragma unroll
    for (int c = 0; c < 8; ++c){
      const bf16x8 bfv = *(const bf16x8*)&sm.ab.B[c * 16 + l16][s * 32 + quad * 8];
      acc[0][c] = __builtin_amdgcn_mfma_f32_16x16x32_bf16(af[0], bfv, acc[0][c], 0, 0, 0);
      acc[1][c] = __builtin_amdgcn_mfma_f32_16x16x32_bf16(af[1], bfv, acc[1][c], 0, 0, 0);
    }
  }

  // ---- epilogue: transpose through LDS, then coalesced float4 stores ----
  __syncthreads();   // everyone done reading A/B before we overwrite as C
  // C/D layout: col = l16, row = quad*4+reg (within each 16x16 tile)
#pragma unroll
  for (int rt = 0; rt < 2; ++rt){
#pragma unroll
    for (int c = 0; c < 8; ++c){
#pragma unroll
      for (int reg = 0; reg < 4; ++reg){
        const int r = wave * 32 + rt * 16 + quad * 4 + reg;
        sm.C[r][c * 16 + l16] = acc[rt][c][reg];   // stride 132: 2-way banks, free
      }
    }
  }
  __syncthreads();

  // thread t, step k: row = k*8 + (t>>5), col = (t&31)*4  -> lane-sequential
  const int rsub = tid >> 5;          // 0..7
  const int col  = (tid & 31) * 4;
#pragma unroll
  for (int k = 0; k < 16; ++k){
    const int row = k * 8 + rsub;
    const int p = p0 + row;
    if (p >= ROWS) continue;
    const floatx4 v = *(const floatx4*)&sm.C[row][col];
    const floatx4 nk = *(const floatx4*)(NkFull + (sIdx[row] << 7) + col);
    floatx4 o;
#pragma unroll
    for (int e = 0; e < 4; ++e) o[e] = nk[e] - v[e];
    if (isF32){
      *(floatx4*)((float*)out + (size_t)p * 128 + col) = o;
    } else {
      ushortx4 ob;
#pragma unroll
      for (int e = 0; e < 4; ++e) ob[e] = f2bf(o[e]);
      *(ushortx4*)((unsigned short*)out + (size_t)p * 128 + col) = ob;
    }
  }
}

extern "C" void kernel_launch(void* const* d_in, const int* in_sizes, int n_in,
                              void* d_out, int out_size, void* d_ws, size_t ws_size,
                              hipStream_t stream) {
  const void* vec = d_in[0];   // (4,16,16,16,16,128)
  const void* Mm  = d_in[1];   // (128,128)
  const void* Ac  = d_in[2];   // (128,256)
  const void* Bb  = d_in[3];   // (256,128)

  unsigned short* pooled = (unsigned short*)d_ws;                 // 202500*128 bf16 = 51.84 MB
  float* NkFull = (float*)((char*)d_ws + NK_OFF);                 // 256*128 fp32 = 128 KB

  nk_kernel<<<128, 256, 0, stream>>>(Ac, Bb, NkFull);
  pool_kernel<<<(POOL_THREADS + 255) / 256, 256, 0, stream>>>(vec, Bb, pooled);
  gemm_kernel<<<(ROWS + 127) / 128, 256, 0, stream>>>(pooled, Mm, NkFull, Bb, d_out);
}

// Round 3
// 267.890 us; speedup vs baseline: 1.0890x; 1.0598x over previous
//
#include <hip/hip_runtime.h>
#include <hip/hip_bf16.h>
#include <stdint.h>

#define MD     128
#define W4     50625
#define ROWS   202500
#define LBAS   256

// ---- new-path ws layout ----
#define P_ELEMS  27648000ull               // 4*16*15*225*128  (b,x1,w2,w34,i) bf16
#define P_BYTES  (P_ELEMS*2ull)            // 55,296,000
#define NK2_OFF  P_BYTES                   // Nk fp32 (256*128) = 131072 B
#define MBF_OFF  (P_BYTES + 131072ull)     // M bf16 (128*128)  = 32768 B
#define WS_NEED  (P_BYTES + 131072ull + 32768ull)

// ---- fallback (R2) ws layout ----
#define NK_OFF 51840000
#define POOL_THREADS 432000

typedef __attribute__((ext_vector_type(8))) __bf16 bf16x8;
typedef __attribute__((ext_vector_type(4))) float floatx4;
typedef __attribute__((ext_vector_type(8))) unsigned short ushortx8;
typedef __attribute__((ext_vector_type(4))) unsigned short ushortx4;

__device__ __forceinline__ float bf2f(unsigned short u){
  union { unsigned int i; float f; } v; v.i = ((unsigned int)u) << 16; return v.f;
}
__device__ __forceinline__ unsigned short f2bf(float x){
  union { float f; unsigned int i; } v; v.f = x;
  unsigned int r = v.i + 0x7FFFu + ((v.i >> 16) & 1u);
  return (unsigned short)(r >> 16);
}
__device__ __forceinline__ int detect_f32(const void* Bbasis){
  return ((const unsigned int*)Bbasis)[0] == 0x3F800000u;   // cos(pi)^4 == 1.0f
}

// ================= K0 (new): Nk table + M->bf16 =================
__global__ __launch_bounds__(256) void nk2_kernel(const void* __restrict__ Acoeff,
                                                  const void* __restrict__ Bbasis,
                                                  const void* __restrict__ Mmat,
                                                  float* __restrict__ NkFull,
                                                  unsigned short* __restrict__ Mbf){
  int gid = blockIdx.x * 256 + threadIdx.x;
  const int isf = detect_f32(Bbasis);
  if (gid < LBAS * MD){
    int idx = gid >> 7, j = gid & 127;
    float a, b;
    if (isf){ a = ((const float*)Acoeff)[j*LBAS+idx]; b = ((const float*)Bbasis)[idx*MD+j]; }
    else    { a = bf2f(((const unsigned short*)Acoeff)[j*LBAS+idx]);
              b = bf2f(((const unsigned short*)Bbasis)[idx*MD+j]); }
    NkFull[gid] = a * b;
  } else {
    int m = gid - LBAS * MD;
    if (m < MD * MD){
      Mbf[m] = isf ? f2bf(((const float*)Mmat)[m]) : ((const unsigned short*)Mmat)[m];
    }
  }
}

// ================= K1 (new): pass A — pool dims 2,3,4 =================
// block = (b, x1, w2, ihalf): stage sum of slabs x2=w2,w2+1 (fp32, LDS),
// then 2x2 window-mean over (x3,x4). Each vec element issued at most twice.
__global__ __launch_bounds__(256) void passA_kernel(const void* __restrict__ vec,
                                                    const void* __restrict__ Bbasis,
                                                    unsigned short* __restrict__ P){
  __shared__ __align__(16) float S[256 * 68];   // [x34][68-padded 64ch] = 69632 B

  const int bid = blockIdx.x;
  const int l   = (bid & 7) * 240 + (bid >> 3);   // XCD-contiguous spans of 240
  const int w2  = l % 15;
  int r = l / 15;
  const int ih  = r & 1;  r >>= 1;
  const int x1  = r & 15;
  const int b   = r >> 4;
  const int t   = threadIdx.x;

  const size_t baseA = ((size_t)((b * 16 + x1) * 16 + w2)) * 32768 + (size_t)ih * 64;
  const size_t baseB = baseA + 32768;            // x2+1 slab
  const int isf = detect_f32(Bbasis);

  if (isf){
    const float* vf = (const float*)vec;
#pragma unroll
    for (int k = 0; k < 16; ++k){
      const int e   = k * 1024 + t * 4;
      const size_t off = (size_t)(e >> 6) * 128 + (e & 63);
      const floatx4 a = *(const floatx4*)(vf + baseA + off);
      const floatx4 c = *(const floatx4*)(vf + baseB + off);
      floatx4 s;
#pragma unroll
      for (int q = 0; q < 4; ++q) s[q] = a[q] + c[q];
      *(floatx4*)&S[(e >> 6) * 68 + (e & 63)] = s;
    }
  } else {
    const unsigned short* vh = (const unsigned short*)vec;
#pragma unroll
    for (int k = 0; k < 16; ++k){
      const int e   = k * 1024 + t * 4;
      const size_t off = (size_t)(e >> 6) * 128 + (e & 63);
      const ushortx4 a = *(const ushortx4*)(vh + baseA + off);
      const ushortx4 c = *(const ushortx4*)(vh + baseB + off);
      floatx4 s;
#pragma unroll
      for (int q = 0; q < 4; ++q) s[q] = bf2f(a[q]) + bf2f(c[q]);
      *(floatx4*)&S[(e >> 6) * 68 + (e & 63)] = s;
    }
  }
  __syncthreads();

  const int ig = t & 7;          // 8 channels
  const int wp = t >> 3;         // 0..31
  unsigned short* Pbase = P + ((size_t)((b * 16 + x1) * 15 + w2)) * 28800 + ih * 64 + ig * 8;
#pragma unroll
  for (int j = 0; j < 8; ++j){
    const int w34 = j * 32 + wp;
    if (w34 < 225){
      const int w3 = w34 / 15;
      const int w4 = w34 - w3 * 15;
      const int p00 = (w3 * 16 + w4) * 68 + ig * 8;
      const float* r00 = &S[p00];
      const float* r01 = &S[p00 + 68];        // w4+1
      const float* r10 = &S[p00 + 68 * 16];   // x3+1
      const float* r11 = &S[p00 + 68 * 17];
      ushortx8 ov;
#pragma unroll
      for (int e = 0; e < 8; ++e){
        const float s = (r00[e] + r01[e]) + (r10[e] + r11[e]);
        ov[e] = f2bf(s * 0.125f);   // mean over x2(2)*x3(2)*x4(2)
      }
      *(ushortx8*)(Pbase + (size_t)w34 * 128) = ov;
    }
  }
}

// ================= K2 (new): pass B — pool dim 1 + GEMM + epilogue =================
// block = (b, w1, w2, half): rows r0..r0+RN of the 225 (w3,w4) windows.
__global__ __launch_bounds__(256) void passB_kernel(const unsigned short* __restrict__ P,
                                                    const float* __restrict__ NkFull,
                                                    const unsigned short* __restrict__ Mbf,
                                                    const void* __restrict__ Bbasis,
                                                    void* __restrict__ out){
  __shared__ __align__(16) unsigned short sAp[128][136];   // 34816 B
  __shared__ __align__(16) unsigned short sB[128][136];    // 34816 B (reused as Ct fp32)
  __shared__ __align__(16) float sNk[16 * 128];            // 8192 B
  __shared__ unsigned char sJ[128];

  const int bid = blockIdx.x;
  const int l   = (bid % 8) * 225 + (bid / 8);   // XCD-contiguous spans of 225
  const int half = l & 1;
  int s2 = l >> 1;
  const int w2 = s2 % 15;  s2 /= 15;
  const int w1 = s2 % 15;
  const int b  = s2 / 15;
  const int r0 = half * 128;
  const int RN = half ? 97 : 128;
  const int t  = threadIdx.x;
  const int isf = detect_f32(Bbasis);

  // ---- stage A (sum 2 x1-slabs), M, Nk, row->idx ----
  {
    const int rr  = t >> 4;
    const int l16 = t & 15;
    const size_t sb0 = ((size_t)((b * 16 + w1) * 15 + w2)) * 28800;
    const size_t sb1 = sb0 + 432000;   // x1+1
#pragma unroll
    for (int it = 0; it < 8; ++it){
      const int row = it * 16 + rr;
      const size_t off = (size_t)(r0 + row) * 128 + l16 * 8;
      const ushortx8 u0 = *(const ushortx8*)(P + sb0 + off);
      const ushortx8 u1 = *(const ushortx8*)(P + sb1 + off);
      ushortx8 sv;
#pragma unroll
      for (int e = 0; e < 8; ++e) sv[e] = f2bf((bf2f(u0[e]) + bf2f(u1[e])) * 0.5f);
      *(ushortx8*)&sAp[row][l16 * 8] = sv;
      *(ushortx8*)&sB[row][l16 * 8] = *(const ushortx8*)(Mbf + row * 128 + l16 * 8);
    }
  }
  {
    const int nkbase = ((w1 & 3) * 4 + (w2 & 3)) * 16;   // j1*4+j2 -> row block of 16
    const floatx4 n0 = *(const floatx4*)(NkFull + nkbase * 128 + t * 8);
    const floatx4 n1 = *(const floatx4*)(NkFull + nkbase * 128 + t * 8 + 4);
    *(floatx4*)&sNk[t * 8]     = n0;
    *(floatx4*)&sNk[t * 8 + 4] = n1;
  }
  if (t < 128){
    const int w34 = r0 + t;
    if (w34 < 225){
      const int w3 = w34 / 15;
      const int w4 = w34 - w3 * 15;
      sJ[t] = (unsigned char)((w3 & 3) * 4 + (w4 & 3));
    } else sJ[t] = 0;
  }
  __syncthreads();

  // ---- MFMA: wave w owns row tiles {w, w+4} ----
  const int wave = t >> 6;
  const int lane = t & 63;
  const int quad = lane >> 4;
  const int l16m = lane & 15;

  floatx4 acc[2][8];
#pragma unroll
  for (int rt = 0; rt < 2; ++rt)
#pragma unroll
    for (int c = 0; c < 8; ++c) acc[rt][c] = (floatx4){0.f, 0.f, 0.f, 0.f};

#pragma unroll
  for (int s = 0; s < 4; ++s){
    const bf16x8 af0 = *(const bf16x8*)&sAp[wave * 16 + l16m][s * 32 + quad * 8];
    const bf16x8 af1 = *(const bf16x8*)&sAp[64 + wave * 16 + l16m][s * 32 + quad * 8];
#pragma unroll
    for (int c = 0; c < 8; ++c){
      const bf16x8 bfv = *(const bf16x8*)&sB[c * 16 + l16m][s * 32 + quad * 8];
      acc[0][c] = __builtin_amdgcn_mfma_f32_16x16x32_bf16(af0, bfv, acc[0][c], 0, 0, 0);
      acc[1][c] = __builtin_amdgcn_mfma_f32_16x16x32_bf16(af1, bfv, acc[1][c], 0, 0, 0);
    }
  }
  __syncthreads();   // done reading sAp/sB; sB region becomes Ct

  // ---- epilogue: 2 sub-chunks of 64 rows through LDS transpose ----
  float* Ct = (float*)&sB[0][0];     // logical [64][132] fp32 = 33792 B
  const size_t prow0 = ((size_t)((b * 15 + w1) * 15 + w2)) * 225 + r0;

#pragma unroll
  for (int s = 0; s < 2; ++s){
    // wave w's acc[s] = tile (4s + w) = local rows wave*16 + quad*4 + reg
#pragma unroll
    for (int c = 0; c < 8; ++c)
#pragma unroll
      for (int reg = 0; reg < 4; ++reg)
        Ct[(wave * 16 + quad * 4 + reg) * 132 + c * 16 + l16m] = acc[s][c][reg];
    __syncthreads();

    const int col = (t & 31) * 4;
#pragma unroll
    for (int k = 0; k < 8; ++k){
      const int lr = k * 8 + (t >> 5);
      const int rloc = 64 * s + lr;
      if (rloc < RN){
        const floatx4 v  = *(const floatx4*)&Ct[lr * 132 + col];
        const floatx4 nk = *(const floatx4*)&sNk[(int)sJ[rloc] * 128 + col];
        floatx4 o;
#pragma unroll
        for (int e = 0; e < 4; ++e) o[e] = nk[e] - v[e];
        const size_t p = prow0 + rloc;
        if (isf){
          *(floatx4*)((float*)out + p * 128 + col) = o;
        } else {
          ushortx4 ob;
#pragma unroll
          for (int e = 0; e < 4; ++e) ob[e] = f2bf(o[e]);
          *(ushortx4*)((unsigned short*)out + p * 128 + col) = ob;
        }
      }
    }
    if (s == 0) __syncthreads();
  }
}

// ===================== fallback path (R2, proven) =====================
__global__ __launch_bounds__(256) void nk_kernel(const void* __restrict__ Acoeff,
                                                 const void* __restrict__ Bbasis,
                                                 float* __restrict__ NkFull){
  int gid = blockIdx.x * 256 + threadIdx.x;
  if (gid >= LBAS * MD) return;
  int idx = gid >> 7, j = gid & 127;
  float a, b;
  if (detect_f32(Bbasis)){
    a = ((const float*)Acoeff)[j * LBAS + idx];
    b = ((const float*)Bbasis)[idx * MD + j];
  } else {
    a = bf2f(((const unsigned short*)Acoeff)[j * LBAS + idx]);
    b = bf2f(((const unsigned short*)Bbasis)[idx * MD + j]);
  }
  NkFull[gid] = a * b;
}

template<int ISF32>
__device__ __forceinline__ void pool_body(const void* __restrict__ vec,
                                          unsigned short* __restrict__ pooled,
                                          int gid){
  const int ig = gid & 31;
  unsigned int strip = (unsigned int)(gid >> 5);
  const unsigned int w4 = strip % 15u; strip /= 15u;
  const unsigned int w3 = strip % 15u; strip /= 15u;
  const unsigned int w2 = strip % 15u;
  const unsigned int b  = strip / 15u;
  const unsigned int base = b*8388608u + w2*32768u + w3*2048u + w4*128u
                          + (unsigned int)(ig * 4);
  unsigned int offs[8];
#pragma unroll
  for (int d = 0; d < 8; ++d){
    const unsigned int d2 = (d>>2)&1u, d3 = (d>>1)&1u, d4 = d&1u;
    offs[d] = base + d2*32768u + d3*2048u + d4*128u;
  }
  const unsigned int prowB = b*50625u + w2*225u + w3*15u + w4;
  float prev[4], cur[4];
#pragma unroll 4
  for (int k1 = 0; k1 < 16; ++k1){
#pragma unroll
    for (int e = 0; e < 4; ++e) cur[e] = 0.f;
#pragma unroll
    for (int d = 0; d < 8; ++d){
      const unsigned int off = offs[d] + (unsigned int)k1 * 524288u;
      if (ISF32){
        const floatx4 v = *(const floatx4*)((const float*)vec + off);
#pragma unroll
        for (int e = 0; e < 4; ++e) cur[e] += v[e];
      } else {
        const ushortx4 u = *(const ushortx4*)((const unsigned short*)vec + off);
#pragma unroll
        for (int e = 0; e < 4; ++e) cur[e] += bf2f(u[e]);
      }
    }
    if (k1 > 0){
      ushortx4 ov;
#pragma unroll
      for (int e = 0; e < 4; ++e) ov[e] = f2bf((prev[e] + cur[e]) * 0.0625f);
      *(ushortx4*)(pooled + (size_t)(prowB + (unsigned)(k1 - 1) * 3375u) * 128 + ig * 4) = ov;
    }
#pragma unroll
    for (int e = 0; e < 4; ++e) prev[e] = cur[e];
  }
}

__global__ __launch_bounds__(256) void pool_kernel(const void* __restrict__ vec,
                                                   const void* __restrict__ Bbasis,
                                                   unsigned short* __restrict__ pooled){
  int gid = blockIdx.x * 256 + threadIdx.x;
  if (gid >= POOL_THREADS) return;
  if (detect_f32(Bbasis)) pool_body<1>(vec, pooled, gid);
  else                    pool_body<0>(vec, pooled, gid);
}

union GemmSmem {
  struct { unsigned short A[128][136]; unsigned short B[128][136]; } ab;
  float C[128][132];
};

__global__ __launch_bounds__(256) void gemm_kernel(const unsigned short* __restrict__ pooled,
                                                   const void* __restrict__ Mmat,
                                                   const float* __restrict__ NkFull,
                                                   const void* __restrict__ Bbasis,
                                                   void* __restrict__ out){
  __shared__ __align__(16) GemmSmem sm;
  __shared__ int sIdx[128];

  const int tid = threadIdx.x;
  const int p0  = blockIdx.x * 128;
  const int isF32 = detect_f32(Bbasis);

  {
    const int rr  = tid >> 4;
    const int l16 = tid & 15;
#pragma unroll
    for (int r8 = 0; r8 < 8; ++r8){
      const int row = r8 * 16 + rr;
      *(ushortx8*)&sm.ab.A[row][l16 * 8] =
          *(const ushortx8*)(pooled + (size_t)(p0 + row) * 128 + l16 * 8);
    }
    if (isF32){
      const float* mf = (const float*)Mmat;
#pragma unroll
      for (int r8 = 0; r8 < 8; ++r8){
        const int row = r8 * 16 + rr;
        const float* src = mf + row * 128 + l16 * 8;
        floatx4 lo = *(const floatx4*)src;
        floatx4 hi = *(const floatx4*)(src + 4);
        ushortx8 v;
#pragma unroll
        for (int e = 0; e < 4; ++e){ v[e] = f2bf(lo[e]); v[4+e] = f2bf(hi[e]); }
        *(ushortx8*)&sm.ab.B[row][l16 * 8] = v;
      }
    } else {
      const unsigned short* mh = (const unsigned short*)Mmat;
#pragma unroll
      for (int r8 = 0; r8 < 8; ++r8){
        const int row = r8 * 16 + rr;
        *(ushortx8*)&sm.ab.B[row][l16 * 8] = *(const ushortx8*)(mh + row * 128 + l16 * 8);
      }
    }
  }
  if (tid < 128){
    const int p = p0 + tid;
    unsigned int w = (p < ROWS) ? (unsigned int)(p % W4) : 0u;
    const unsigned int w4 = w % 15u; w /= 15u;
    const unsigned int w3 = w % 15u; w /= 15u;
    const unsigned int w2 = w % 15u;
    const unsigned int w1 = w / 15u;
    sIdx[tid] = (int)(((w1 & 3u) << 6) | ((w2 & 3u) << 4) | ((w3 & 3u) << 2) | (w4 & 3u));
  }
  __syncthreads();

  const int wave = tid >> 6;
  const int lane = tid & 63;
  const int quad = lane >> 4;
  const int l16  = lane & 15;

  floatx4 acc[2][8];
#pragma unroll
  for (int rt = 0; rt < 2; ++rt)
#pragma unroll
    for (int c = 0; c < 8; ++c) acc[rt][c] = (floatx4){0.f, 0.f, 0.f, 0.f};

#pragma unroll
  for (int s = 0; s < 4; ++s){
    bf16x8 af[2];
#pragma unroll
    for (int rt = 0; rt < 2; ++rt)
      af[rt] = *(const bf16x8*)&sm.ab.A[wave * 32 + rt * 16 + l16][s * 32 + quad * 8];
#pragma unroll
    for (int c = 0; c < 8; ++c){
      const bf16x8 bfv = *(const bf16x8*)&sm.ab.B[c * 16 + l16][s * 32 + quad * 8];
      acc[0][c] = __builtin_amdgcn_mfma_f32_16x16x32_bf16(af[0], bfv, acc[0][c], 0, 0, 0);
      acc[1][c] = __builtin_amdgcn_mfma_f32_16x16x32_bf16(af[1], bfv, acc[1][c], 0, 0, 0);
    }
  }

  __syncthreads();
#pragma unroll
  for (int rt = 0; rt < 2; ++rt){
#pragma unroll
    for (int c = 0; c < 8; ++c){
#pragma unroll
      for (int reg = 0; reg < 4; ++reg){
        const int r = wave * 32 + rt * 16 + quad * 4 + reg;
        sm.C[r][c * 16 + l16] = acc[rt][c][reg];
      }
    }
  }
  __syncthreads();

  const int rsub = tid >> 5;
  const int col  = (tid & 31) * 4;
#pragma unroll
  for (int k = 0; k < 16; ++k){
    const int row = k * 8 + rsub;
    const int p = p0 + row;
    if (p >= ROWS) continue;
    const floatx4 v = *(const floatx4*)&sm.C[row][col];
    const floatx4 nk = *(const floatx4*)(NkFull + (sIdx[row] << 7) + col);
    floatx4 o;
#pragma unroll
    for (int e = 0; e < 4; ++e) o[e] = nk[e] - v[e];
    if (isF32){
      *(floatx4*)((float*)out + (size_t)p * 128 + col) = o;
    } else {
      ushortx4 ob;
#pragma unroll
      for (int e = 0; e < 4; ++e) ob[e] = f2bf(o[e]);
      *(ushortx4*)((unsigned short*)out + (size_t)p * 128 + col) = ob;
    }
  }
}

extern "C" void kernel_launch(void* const* d_in, const int* in_sizes, int n_in,
                              void* d_out, int out_size, void* d_ws, size_t ws_size,
                              hipStream_t stream) {
  const void* vec = d_in[0];
  const void* Mm  = d_in[1];
  const void* Ac  = d_in[2];
  const void* Bb  = d_in[3];

  if (ws_size >= WS_NEED){
    unsigned short* P = (unsigned short*)d_ws;
    float* NkFull = (float*)((char*)d_ws + NK2_OFF);
    unsigned short* Mbf = (unsigned short*)((char*)d_ws + MBF_OFF);
    nk2_kernel<<<192, 256, 0, stream>>>(Ac, Bb, Mm, NkFull, Mbf);
    passA_kernel<<<1920, 256, 0, stream>>>(vec, Bb, P);
    passB_kernel<<<1800, 256, 0, stream>>>(P, NkFull, Mbf, Bb, d_out);
  } else {
    unsigned short* pooled = (unsigned short*)d_ws;
    float* NkFull = (float*)((char*)d_ws + NK_OFF);
    nk_kernel<<<128, 256, 0, stream>>>(Ac, Bb, NkFull);
    pool_kernel<<<(POOL_THREADS + 255) / 256, 256, 0, stream>>>(vec, Bb, pooled);
    gemm_kernel<<<(ROWS + 127) / 128, 256, 0, stream>>>(pooled, Mm, NkFull, Bb, d_out);
  }
}

// Round 4
// 264.782 us; speedup vs baseline: 1.1018x; 1.0117x over previous
//
#include <hip/hip_runtime.h>
#include <hip/hip_bf16.h>
#include <stdint.h>

#define MD     128
#define W4     50625
#define ROWS   202500
#define LBAS   256

// ---- new-path ws layout ----
// P layout: [b][x1][w2][chq(4)][w34(225)][ch32]  (bf16)
#define P_ELEMS  27648000ull               // 4*16*15*4*225*32
#define P_BYTES  (P_ELEMS*2ull)            // 55,296,000
#define NK2_OFF  P_BYTES                   // Nk fp32 (256*128) = 131072 B
#define MBF_OFF  (P_BYTES + 131072ull)     // M bf16 (128*128)  = 32768 B
#define WS_NEED  (P_BYTES + 131072ull + 32768ull)

// ---- fallback (R2) ws layout ----
#define NK_OFF 51840000
#define POOL_THREADS 432000

typedef __attribute__((ext_vector_type(8))) __bf16 bf16x8;
typedef __attribute__((ext_vector_type(4))) float floatx4;
typedef __attribute__((ext_vector_type(8))) unsigned short ushortx8;
typedef __attribute__((ext_vector_type(4))) unsigned short ushortx4;

__device__ __forceinline__ float bf2f(unsigned short u){
  union { unsigned int i; float f; } v; v.i = ((unsigned int)u) << 16; return v.f;
}
__device__ __forceinline__ unsigned short f2bf(float x){
  union { float f; unsigned int i; } v; v.f = x;
  unsigned int r = v.i + 0x7FFFu + ((v.i >> 16) & 1u);
  return (unsigned short)(r >> 16);
}
__device__ __forceinline__ int detect_f32(const void* Bbasis){
  return ((const unsigned int*)Bbasis)[0] == 0x3F800000u;   // cos(pi)^4 == 1.0f
}

// ================= K0: Nk table + M->bf16 =================
__global__ __launch_bounds__(256) void nk2_kernel(const void* __restrict__ Acoeff,
                                                  const void* __restrict__ Bbasis,
                                                  const void* __restrict__ Mmat,
                                                  float* __restrict__ NkFull,
                                                  unsigned short* __restrict__ Mbf){
  int gid = blockIdx.x * 256 + threadIdx.x;
  const int isf = detect_f32(Bbasis);
  if (gid < LBAS * MD){
    int idx = gid >> 7, j = gid & 127;
    float a, b;
    if (isf){ a = ((const float*)Acoeff)[j*LBAS+idx]; b = ((const float*)Bbasis)[idx*MD+j]; }
    else    { a = bf2f(((const unsigned short*)Acoeff)[j*LBAS+idx]);
              b = bf2f(((const unsigned short*)Bbasis)[idx*MD+j]); }
    NkFull[gid] = a * b;
  } else {
    int m = gid - LBAS * MD;
    if (m < MD * MD){
      Mbf[m] = isf ? f2bf(((const float*)Mmat)[m]) : ((const unsigned short*)Mmat)[m];
    }
  }
}

// ================= K1: pass A — pool dims 2,3,4 (two 32-ch phases) =================
// block = (b, x1, w2, ihalf64); LDS 36.9 KB -> 4 blocks/CU.
__global__ __launch_bounds__(256, 4) void passA_kernel(const void* __restrict__ vec,
                                                       const void* __restrict__ Bbasis,
                                                       unsigned short* __restrict__ P){
  __shared__ __align__(16) float S[256 * 36];   // [x34][36-padded 32ch] = 36864 B

  const int bid = blockIdx.x;
  const int l   = (bid & 7) * 240 + (bid >> 3);   // XCD swizzle
  const int w2  = l % 15;
  int r = l / 15;
  const int ih  = r & 1;  r >>= 1;
  const int x1  = r & 15;
  const int b   = r >> 4;
  const int t   = threadIdx.x;
  const int isf = detect_f32(Bbasis);

  const size_t slab0 = ((size_t)((b * 16 + x1) * 16 + w2)) * 32768;  // elems
  unsigned short* Pblk = P + ((size_t)((b * 16 + x1) * 15 + w2)) * 28800;

#pragma unroll
  for (int half = 0; half < 2; ++half){
    const int chb = ih * 64 + half * 32;
    if (half) __syncthreads();
    if (isf){
      const float* vf = (const float*)vec;
#pragma unroll
      for (int k = 0; k < 8; ++k){
        const int f   = k * 256 + t;       // 0..2047 float4-chunks
        const int row = f >> 3;            // x34
        const int c4  = f & 7;
        const size_t off = slab0 + (size_t)row * 128 + chb + c4 * 4;
        const floatx4 a = *(const floatx4*)(vf + off);
        const floatx4 c = *(const floatx4*)(vf + off + 32768);
        floatx4 s;
#pragma unroll
        for (int q = 0; q < 4; ++q) s[q] = a[q] + c[q];
        *(floatx4*)&S[row * 36 + c4 * 4] = s;
      }
    } else {
      const unsigned short* vh = (const unsigned short*)vec;
#pragma unroll
      for (int k = 0; k < 4; ++k){
        const int f   = k * 256 + t;       // 0..1023 ushortx8-chunks
        const int row = f >> 2;
        const int c8  = f & 3;
        const size_t off = slab0 + (size_t)row * 128 + chb + c8 * 8;
        const ushortx8 a = *(const ushortx8*)(vh + off);
        const ushortx8 c = *(const ushortx8*)(vh + off + 32768);
        floatx4 s0, s1;
#pragma unroll
        for (int q = 0; q < 4; ++q){ s0[q] = bf2f(a[q]) + bf2f(c[q]);
                                     s1[q] = bf2f(a[4+q]) + bf2f(c[4+q]); }
        *(floatx4*)&S[row * 36 + c8 * 8]     = s0;
        *(floatx4*)&S[row * 36 + c8 * 8 + 4] = s1;
      }
    }
    __syncthreads();

    // pool x3,x4 (2x2) and write chunk chq = ih*2+half, contiguous 225x32 bf16
    unsigned short* Pdst = Pblk + (size_t)(ih * 2 + half) * 7200;
#pragma unroll
    for (int j = 0; j < 4; ++j){
      const int o = j * 256 + t;           // 0..899
      if (o < 900){
        const int w34 = o >> 2;
        const int c8  = (o & 3) * 8;
        const int w3  = w34 / 15;
        const int w4  = w34 - w3 * 15;
        const int p00 = (w3 * 16 + w4) * 36 + c8;
        const float* r00 = &S[p00];
        const float* r01 = &S[p00 + 36];        // x4+1
        const float* r10 = &S[p00 + 576];       // x3+1
        const float* r11 = &S[p00 + 612];
        ushortx8 ov;
#pragma unroll
        for (int e = 0; e < 8; ++e)
          ov[e] = f2bf(((r00[e] + r01[e]) + (r10[e] + r11[e])) * 0.125f);
        *(ushortx8*)(Pdst + (size_t)w34 * 32 + c8) = ov;
      }
    }
  }
}

// ================= K2: pass B — pool dim 1 + GEMM (K split 2x64) + epilogue ======
// LDS = 2*18432 + 8192 + 128 = 45.2 KB -> 3 blocks/CU.
__global__ __launch_bounds__(256, 3) void passB_kernel(const unsigned short* __restrict__ P,
                                                       const float* __restrict__ NkFull,
                                                       const unsigned short* __restrict__ Mbf,
                                                       const void* __restrict__ Bbasis,
                                                       void* __restrict__ out){
  __shared__ __align__(16) unsigned short sAB[2][128][72];  // [0]=A, [1]=B; 36864 B
  __shared__ __align__(16) float sNk[16 * 128];             // 8192 B
  __shared__ unsigned char sJ[128];

  const int bid = blockIdx.x;
  const int l   = (bid % 8) * 225 + (bid / 8);   // XCD swizzle
  const int half = l & 1;
  int s2 = l >> 1;
  const int w2 = s2 % 15;  s2 /= 15;
  const int w1 = s2 % 15;
  const int b  = s2 / 15;
  const int r0 = half * 128;
  const int RN = half ? 97 : 128;
  const int t  = threadIdx.x;
  const int isf = detect_f32(Bbasis);

  const size_t sb0 = ((size_t)((b * 16 + w1) * 15 + w2)) * 28800;
  const size_t sb1 = sb0 + 432000;   // x1+1

  // Nk + sJ staging (once)
  {
    const int nkbase = ((w1 & 3) * 4 + (w2 & 3)) * 16;
    *(floatx4*)&sNk[t * 8]     = *(const floatx4*)(NkFull + nkbase * 128 + t * 8);
    *(floatx4*)&sNk[t * 8 + 4] = *(const floatx4*)(NkFull + nkbase * 128 + t * 8 + 4);
  }
  if (t < 128){
    const int w34 = r0 + t;
    if (w34 < 225){
      const int w3 = w34 / 15;
      const int w4 = w34 - w3 * 15;
      sJ[t] = (unsigned char)((w3 & 3) * 4 + (w4 & 3));
    } else sJ[t] = 0;
  }

  const int wave = t >> 6;
  const int lane = t & 63;
  const int quad = lane >> 4;
  const int l16m = lane & 15;

  floatx4 acc[2][8];
#pragma unroll
  for (int rt = 0; rt < 2; ++rt)
#pragma unroll
    for (int c = 0; c < 8; ++c) acc[rt][c] = (floatx4){0.f, 0.f, 0.f, 0.f};

  const int l8 = t & 7;            // column group (8 ch of the 64)
  const int rr = t >> 3;           // 0..31

#pragma unroll
  for (int kh = 0; kh < 2; ++kh){
    if (kh) __syncthreads();       // everyone done with previous half's tiles
    // stage A (sum x1-pair) and B for this 64-ch K-half
    const int chq = kh * 2 + (l8 >> 2);
    const int cw  = (l8 & 3) * 8;
#pragma unroll
    for (int it = 0; it < 4; ++it){
      const int row  = it * 32 + rr;
      const int rowg = (r0 + row < 225) ? (r0 + row) : 224;   // clamp OOB tail
      const size_t off = (size_t)chq * 7200 + (size_t)rowg * 32 + cw;
      const ushortx8 u0 = *(const ushortx8*)(P + sb0 + off);
      const ushortx8 u1 = *(const ushortx8*)(P + sb1 + off);
      ushortx8 sv;
#pragma unroll
      for (int e = 0; e < 8; ++e) sv[e] = f2bf((bf2f(u0[e]) + bf2f(u1[e])) * 0.5f);
      *(ushortx8*)&sAB[0][row][l8 * 8] = sv;
      *(ushortx8*)&sAB[1][row][l8 * 8] =
          *(const ushortx8*)(Mbf + row * 128 + kh * 64 + l8 * 8);
    }
    __syncthreads();

#pragma unroll
    for (int s = 0; s < 2; ++s){
      const bf16x8 af0 = *(const bf16x8*)&sAB[0][wave * 16 + l16m][s * 32 + quad * 8];
      const bf16x8 af1 = *(const bf16x8*)&sAB[0][64 + wave * 16 + l16m][s * 32 + quad * 8];
#pragma unroll
      for (int c = 0; c < 8; ++c){
        const bf16x8 bfv = *(const bf16x8*)&sAB[1][c * 16 + l16m][s * 32 + quad * 8];
        acc[0][c] = __builtin_amdgcn_mfma_f32_16x16x32_bf16(af0, bfv, acc[0][c], 0, 0, 0);
        acc[1][c] = __builtin_amdgcn_mfma_f32_16x16x32_bf16(af1, bfv, acc[1][c], 0, 0, 0);
      }
    }
  }
  __syncthreads();   // tiles free; reuse as Ct

  // ---- epilogue: 2 sub-chunks of 64 rows through LDS transpose ----
  float* Ct = (float*)&sAB[0][0][0];     // 64*132*4 = 33792 B <= 36864
  const size_t prow0 = ((size_t)((b * 15 + w1) * 15 + w2)) * 225 + r0;

#pragma unroll
  for (int s = 0; s < 2; ++s){
#pragma unroll
    for (int c = 0; c < 8; ++c)
#pragma unroll
      for (int reg = 0; reg < 4; ++reg)
        Ct[(wave * 16 + quad * 4 + reg) * 132 + c * 16 + l16m] = acc[s][c][reg];
    __syncthreads();

    const int col = (t & 31) * 4;
#pragma unroll
    for (int k = 0; k < 8; ++k){
      const int lr = k * 8 + (t >> 5);
      const int rloc = 64 * s + lr;
      if (rloc < RN){
        const floatx4 v  = *(const floatx4*)&Ct[lr * 132 + col];
        const floatx4 nk = *(const floatx4*)&sNk[(int)sJ[rloc] * 128 + col];
        floatx4 o;
#pragma unroll
        for (int e = 0; e < 4; ++e) o[e] = nk[e] - v[e];
        const size_t p = prow0 + rloc;
        if (isf){
          *(floatx4*)((float*)out + p * 128 + col) = o;
        } else {
          ushortx4 ob;
#pragma unroll
          for (int e = 0; e < 4; ++e) ob[e] = f2bf(o[e]);
          *(ushortx4*)((unsigned short*)out + p * 128 + col) = ob;
        }
      }
    }
    if (s == 0) __syncthreads();
  }
}

// ===================== fallback path (R2, proven) =====================
__global__ __launch_bounds__(256) void nk_kernel(const void* __restrict__ Acoeff,
                                                 const void* __restrict__ Bbasis,
                                                 float* __restrict__ NkFull){
  int gid = blockIdx.x * 256 + threadIdx.x;
  if (gid >= LBAS * MD) return;
  int idx = gid >> 7, j = gid & 127;
  float a, b;
  if (detect_f32(Bbasis)){
    a = ((const float*)Acoeff)[j * LBAS + idx];
    b = ((const float*)Bbasis)[idx * MD + j];
  } else {
    a = bf2f(((const unsigned short*)Acoeff)[j * LBAS + idx]);
    b = bf2f(((const unsigned short*)Bbasis)[idx * MD + j]);
  }
  NkFull[gid] = a * b;
}

template<int ISF32>
__device__ __forceinline__ void pool_body(const void* __restrict__ vec,
                                          unsigned short* __restrict__ pooled,
                                          int gid){
  const int ig = gid & 31;
  unsigned int strip = (unsigned int)(gid >> 5);
  const unsigned int w4 = strip % 15u; strip /= 15u;
  const unsigned int w3 = strip % 15u; strip /= 15u;
  const unsigned int w2 = strip % 15u;
  const unsigned int b  = strip / 15u;
  const unsigned int base = b*8388608u + w2*32768u + w3*2048u + w4*128u
                          + (unsigned int)(ig * 4);
  unsigned int offs[8];
#pragma unroll
  for (int d = 0; d < 8; ++d){
    const unsigned int d2 = (d>>2)&1u, d3 = (d>>1)&1u, d4 = d&1u;
    offs[d] = base + d2*32768u + d3*2048u + d4*128u;
  }
  const unsigned int prowB = b*50625u + w2*225u + w3*15u + w4;
  float prev[4], cur[4];
#pragma unroll 4
  for (int k1 = 0; k1 < 16; ++k1){
#pragma unroll
    for (int e = 0; e < 4; ++e) cur[e] = 0.f;
#pragma unroll
    for (int d = 0; d < 8; ++d){
      const unsigned int off = offs[d] + (unsigned int)k1 * 524288u;
      if (ISF32){
        const floatx4 v = *(const floatx4*)((const float*)vec + off);
#pragma unroll
        for (int e = 0; e < 4; ++e) cur[e] += v[e];
      } else {
        const ushortx4 u = *(const ushortx4*)((const unsigned short*)vec + off);
#pragma unroll
        for (int e = 0; e < 4; ++e) cur[e] += bf2f(u[e]);
      }
    }
    if (k1 > 0){
      ushortx4 ov;
#pragma unroll
      for (int e = 0; e < 4; ++e) ov[e] = f2bf((prev[e] + cur[e]) * 0.0625f);
      *(ushortx4*)(pooled + (size_t)(prowB + (unsigned)(k1 - 1) * 3375u) * 128 + ig * 4) = ov;
    }
#pragma unroll
    for (int e = 0; e < 4; ++e) prev[e] = cur[e];
  }
}

__global__ __launch_bounds__(256) void pool_kernel(const void* __restrict__ vec,
                                                   const void* __restrict__ Bbasis,
                                                   unsigned short* __restrict__ pooled){
  int gid = blockIdx.x * 256 + threadIdx.x;
  if (gid >= POOL_THREADS) return;
  if (detect_f32(Bbasis)) pool_body<1>(vec, pooled, gid);
  else                    pool_body<0>(vec, pooled, gid);
}

union GemmSmem {
  struct { unsigned short A[128][136]; unsigned short B[128][136]; } ab;
  float C[128][132];
};

__global__ __launch_bounds__(256) void gemm_kernel(const unsigned short* __restrict__ pooled,
                                                   const void* __restrict__ Mmat,
                                                   const float* __restrict__ NkFull,
                                                   const void* __restrict__ Bbasis,
                                                   void* __restrict__ out){
  __shared__ __align__(16) GemmSmem sm;
  __shared__ int sIdx[128];

  const int tid = threadIdx.x;
  const int p0  = blockIdx.x * 128;
  const int isF32 = detect_f32(Bbasis);

  {
    const int rr  = tid >> 4;
    const int l16 = tid & 15;
#pragma unroll
    for (int r8 = 0; r8 < 8; ++r8){
      const int row = r8 * 16 + rr;
      *(ushortx8*)&sm.ab.A[row][l16 * 8] =
          *(const ushortx8*)(pooled + (size_t)(p0 + row) * 128 + l16 * 8);
    }
    if (isF32){
      const float* mf = (const float*)Mmat;
#pragma unroll
      for (int r8 = 0; r8 < 8; ++r8){
        const int row = r8 * 16 + rr;
        const float* src = mf + row * 128 + l16 * 8;
        floatx4 lo = *(const floatx4*)src;
        floatx4 hi = *(const floatx4*)(src + 4);
        ushortx8 v;
#pragma unroll
        for (int e = 0; e < 4; ++e){ v[e] = f2bf(lo[e]); v[4+e] = f2bf(hi[e]); }
        *(ushortx8*)&sm.ab.B[row][l16 * 8] = v;
      }
    } else {
      const unsigned short* mh = (const unsigned short*)Mmat;
#pragma unroll
      for (int r8 = 0; r8 < 8; ++r8){
        const int row = r8 * 16 + rr;
        *(ushortx8*)&sm.ab.B[row][l16 * 8] = *(const ushortx8*)(mh + row * 128 + l16 * 8);
      }
    }
  }
  if (tid < 128){
    const int p = p0 + tid;
    unsigned int w = (p < ROWS) ? (unsigned int)(p % W4) : 0u;
    const unsigned int w4 = w % 15u; w /= 15u;
    const unsigned int w3 = w % 15u; w /= 15u;
    const unsigned int w2 = w % 15u;
    const unsigned int w1 = w / 15u;
    sIdx[tid] = (int)(((w1 & 3u) << 6) | ((w2 & 3u) << 4) | ((w3 & 3u) << 2) | (w4 & 3u));
  }
  __syncthreads();

  const int wave = tid >> 6;
  const int lane = tid & 63;
  const int quad = lane >> 4;
  const int l16  = lane & 15;

  floatx4 acc[2][8];
#pragma unroll
  for (int rt = 0; rt < 2; ++rt)
#pragma unroll
    for (int c = 0; c < 8; ++c) acc[rt][c] = (floatx4){0.f, 0.f, 0.f, 0.f};

#pragma unroll
  for (int s = 0; s < 4; ++s){
    bf16x8 af[2];
#pragma unroll
    for (int rt = 0; rt < 2; ++rt)
      af[rt] = *(const bf16x8*)&sm.ab.A[wave * 32 + rt * 16 + l16][s * 32 + quad * 8];
#pragma unroll
    for (int c = 0; c < 8; ++c){
      const bf16x8 bfv = *(const bf16x8*)&sm.ab.B[c * 16 + l16][s * 32 + quad * 8];
      acc[0][c] = __builtin_amdgcn_mfma_f32_16x16x32_bf16(af[0], bfv, acc[0][c], 0, 0, 0);
      acc[1][c] = __builtin_amdgcn_mfma_f32_16x16x32_bf16(af[1], bfv, acc[1][c], 0, 0, 0);
    }
  }

  __syncthreads();
#pragma unroll
  for (int rt = 0; rt < 2; ++rt){
#pragma unroll
    for (int c = 0; c < 8; ++c){
#pragma unroll
      for (int reg = 0; reg < 4; ++reg){
        const int r = wave * 32 + rt * 16 + quad * 4 + reg;
        sm.C[r][c * 16 + l16] = acc[rt][c][reg];
      }
    }
  }
  __syncthreads();

  const int rsub = tid >> 5;
  const int col  = (tid & 31) * 4;
#pragma unroll
  for (int k = 0; k < 16; ++k){
    const int row = k * 8 + rsub;
    const int p = p0 + row;
    if (p >= ROWS) continue;
    const floatx4 v = *(const floatx4*)&sm.C[row][col];
    const floatx4 nk = *(const floatx4*)(NkFull + (sIdx[row] << 7) + col);
    floatx4 o;
#pragma unroll
    for (int e = 0; e < 4; ++e) o[e] = nk[e] - v[e];
    if (isF32){
      *(floatx4*)((float*)out + (size_t)p * 128 + col) = o;
    } else {
      ushortx4 ob;
#pragma unroll
      for (int e = 0; e < 4; ++e) ob[e] = f2bf(o[e]);
      *(ushortx4*)((unsigned short*)out + (size_t)p * 128 + col) = ob;
    }
  }
}

extern "C" void kernel_launch(void* const* d_in, const int* in_sizes, int n_in,
                              void* d_out, int out_size, void* d_ws, size_t ws_size,
                              hipStream_t stream) {
  const void* vec = d_in[0];
  const void* Mm  = d_in[1];
  const void* Ac  = d_in[2];
  const void* Bb  = d_in[3];

  if (ws_size >= WS_NEED){
    unsigned short* P = (unsigned short*)d_ws;
    float* NkFull = (float*)((char*)d_ws + NK2_OFF);
    unsigned short* Mbf = (unsigned short*)((char*)d_ws + MBF_OFF);
    nk2_kernel<<<192, 256, 0, stream>>>(Ac, Bb, Mm, NkFull, Mbf);
    passA_kernel<<<1920, 256, 0, stream>>>(vec, Bb, P);
    passB_kernel<<<1800, 256, 0, stream>>>(P, NkFull, Mbf, Bb, d_out);
  } else {
    unsigned short* pooled = (unsigned short*)d_ws;
    float* NkFull = (float*)((char*)d_ws + NK_OFF);
    nk_kernel<<<128, 256, 0, stream>>>(Ac, Bb, NkFull);
    pool_kernel<<<(POOL_THREADS + 255) / 256, 256, 0, stream>>>(vec, Bb, pooled);
    gemm_kernel<<<(ROWS + 127) / 128, 256, 0, stream>>>(pooled, Mm, NkFull, Bb, d_out);
  }
}

// Round 5
// 249.951 us; speedup vs baseline: 1.1671x; 1.0593x over previous
//
#include <hip/hip_runtime.h>
#include <hip/hip_bf16.h>
#include <stdint.h>

#define MD   128
#define LBAS 256

// ws layout: NkFull fp32 (256x128) @0, Mbf bf16 (128x128) @131072
#define MBF_OFF 131072ull
#define WS_NEED (131072ull + 32768ull)

typedef __attribute__((ext_vector_type(8))) __bf16 bf16x8;
typedef __attribute__((ext_vector_type(4))) float floatx4;
typedef __attribute__((ext_vector_type(8))) unsigned short ushortx8;
typedef __attribute__((ext_vector_type(4))) unsigned short ushortx4;

__device__ __forceinline__ float bf2f(unsigned short u){
  union { unsigned int i; float f; } v; v.i = ((unsigned int)u) << 16; return v.f;
}
__device__ __forceinline__ unsigned short f2bf(float x){
  union { float f; unsigned int i; } v; v.f = x;
  unsigned int r = v.i + 0x7FFFu + ((v.i >> 16) & 1u);
  return (unsigned short)(r >> 16);
}
__device__ __forceinline__ int detect_f32(const void* Bbasis){
  return ((const unsigned int*)Bbasis)[0] == 0x3F800000u;   // cos(pi)^4 == 1.0f
}

// ================= K0: Nk table + M->bf16 =================
__global__ __launch_bounds__(256) void nk2_kernel(const void* __restrict__ Acoeff,
                                                  const void* __restrict__ Bbasis,
                                                  const void* __restrict__ Mmat,
                                                  float* __restrict__ NkFull,
                                                  unsigned short* __restrict__ Mbf){
  int gid = blockIdx.x * 256 + threadIdx.x;
  const int isf = detect_f32(Bbasis);
  if (gid < LBAS * MD){
    int idx = gid >> 7, j = gid & 127;
    float a, b;
    if (isf){ a = ((const float*)Acoeff)[j*LBAS+idx]; b = ((const float*)Bbasis)[idx*MD+j]; }
    else    { a = bf2f(((const unsigned short*)Acoeff)[j*LBAS+idx]);
              b = bf2f(((const unsigned short*)Bbasis)[idx*MD+j]); }
    NkFull[gid] = a * b;
  } else {
    int m = gid - LBAS * MD;
    if (m < MD * MD){
      Mbf[m] = isf ? f2bf(((const float*)Mmat)[m]) : ((const unsigned short*)Mmat)[m];
    }
  }
}

// ================= K1: fused pool(2^4) + GEMM + epilogue =================
// block = (b, w2, w3); loop x1=0..15; pooled-234 ping-pong in LDS;
// A = avg of consecutive x1 slabs; MFMA vs LDS M; 15 out rows per step.
// LDS = 16896(S/Ct) + 34816(M) + 8160(pp) + 4352(Ab) + 2048(Nk) = 66272 B -> 2 blocks/CU.
__global__ __launch_bounds__(256, 2) void mega_kernel(const void* __restrict__ vec,
                                                      const float* __restrict__ NkFull,
                                                      const unsigned short* __restrict__ Mbf,
                                                      const void* __restrict__ Bbasis,
                                                      void* __restrict__ out){
  __shared__ __align__(16) float S[32 * 132];                  // staging; aliased as Ct
  __shared__ __align__(16) unsigned short Mb[128][136];
  __shared__ __align__(16) unsigned short pp[2][15][136];      // pooled-234 ping-pong (bf16)
  __shared__ __align__(16) unsigned short Ab[16 * 136];        // A-tile (row 15 unused)
  __shared__ __align__(16) float sNkStep[512];                 // 4 j4-rows x 128

  // --- block decode: XCD-group same-b blocks (xcd = bid&7 -> {2b,2b+1}) ---
  const int xcd  = blockIdx.x & 7;
  const int slot = blockIdx.x >> 3;
  const int b    = xcd >> 1;
  const int s    = slot * 2 + (xcd & 1);
  if (s >= 225) return;
  const int w3 = s / 15;
  const int w2 = s - w3 * 15;
  const int t  = threadIdx.x;
  const int isf = detect_f32(Bbasis);

  // --- stage M (bf16) ---
#pragma unroll
  for (int k = 0; k < 8; ++k){
    const int f = k * 256 + t;
    const int row = f >> 4, c8 = (f & 15) * 8;
    *(ushortx8*)&Mb[row][c8] = *(const ushortx8*)(Mbf + row * 128 + c8);
  }

  // vec strides (elems): b 8388608, x1 524288, x2 32768, x3 2048, x4 128
  const size_t vbase0 = (size_t)b * 8388608 + (size_t)w2 * 32768 + (size_t)w3 * 2048;

  // --- per-thread static offsets ---
  int offF[4];   // fp32: 4 float4-chunks
#pragma unroll
  for (int k = 0; k < 4; ++k){
    const int ci = k * 256 + t;          // 0..1023
    const int row = ci >> 5;             // x3sub*16 + x4
    offF[k] = (row >> 4) * 2048 + (row & 15) * 128 + (ci & 31) * 4;
  }
  int offB[2];   // bf16: 2 ushortx8-chunks
#pragma unroll
  for (int k = 0; k < 2; ++k){
    const int ci = k * 256 + t;          // 0..511
    const int row = ci >> 4;
    offB[k] = (row >> 4) * 2048 + (row & 15) * 128 + (ci & 15) * 8;
  }

  floatx4 pre[4][2];   // prefetch regs (bf16 path bit-casts into pre[0..1])

  // --- prefetch x1 = 0 ---
  if (isf){
    const float* vf = (const float*)vec + vbase0;
#pragma unroll
    for (int k = 0; k < 4; ++k){
      pre[k][0] = *(const floatx4*)(vf + offF[k]);
      pre[k][1] = *(const floatx4*)(vf + offF[k] + 32768);
    }
  } else {
    const unsigned short* vh = (const unsigned short*)vec + vbase0;
#pragma unroll
    for (int k = 0; k < 2; ++k){
      *(ushortx8*)&pre[k][0] = *(const ushortx8*)(vh + offB[k]);
      *(ushortx8*)&pre[k][1] = *(const ushortx8*)(vh + offB[k] + 32768);
    }
  }

  const int pw4 = t >> 4;            // pooling coords (t<240 active)
  const int pc8 = (t & 15) * 8;
  const int wave = t >> 6, lane = t & 63;
  const int quad = lane >> 4, l16 = lane & 15;

  for (int x1 = 0; x1 < 16; ++x1){
    __syncthreads();   // S free (prev stores done) / M staged

    // ---- regs -> S (x2-pair sum) ----
    if (isf){
#pragma unroll
      for (int k = 0; k < 4; ++k){
        const int ci = k * 256 + t;
        const int row = ci >> 5, c4 = (ci & 31) * 4;
        floatx4 sv;
#pragma unroll
        for (int q = 0; q < 4; ++q) sv[q] = pre[k][0][q] + pre[k][1][q];
        *(floatx4*)&S[row * 132 + c4] = sv;
      }
    } else {
#pragma unroll
      for (int k = 0; k < 2; ++k){
        const int ci = k * 256 + t;
        const int row = ci >> 4, c8 = (ci & 15) * 8;
        const ushortx8 a = *(const ushortx8*)&pre[k][0];
        const ushortx8 c = *(const ushortx8*)&pre[k][1];
#pragma unroll
        for (int q = 0; q < 8; ++q) S[row * 132 + c8 + q] = bf2f(a[q]) + bf2f(c[q]);
      }
    }

    // ---- prefetch x1+1 (overlaps everything below) ----
    if (x1 < 15){
      if (isf){
        const float* vf = (const float*)vec + vbase0 + (size_t)(x1 + 1) * 524288;
#pragma unroll
        for (int k = 0; k < 4; ++k){
          pre[k][0] = *(const floatx4*)(vf + offF[k]);
          pre[k][1] = *(const floatx4*)(vf + offF[k] + 32768);
        }
      } else {
        const unsigned short* vh = (const unsigned short*)vec + vbase0 + (size_t)(x1 + 1) * 524288;
#pragma unroll
        for (int k = 0; k < 2; ++k){
          *(ushortx8*)&pre[k][0] = *(const ushortx8*)(vh + offB[k]);
          *(ushortx8*)&pre[k][1] = *(const ushortx8*)(vh + offB[k] + 32768);
        }
      }
    }
    __syncthreads();   // S ready

    // ---- pool x3,x4 (2x2) + A-tile build ----
    const int cb = x1 & 1, pbuf = cb ^ 1;
    if (t < 240){
      float cur[8];
      const int p0 = pw4 * 132 + pc8;
#pragma unroll
      for (int e = 0; e < 8; ++e)
        cur[e] = ((S[p0 + e] + S[p0 + 132 + e]) +
                  (S[p0 + 16 * 132 + e] + S[p0 + 17 * 132 + e])) * 0.125f;
      ushortx8 cv;
#pragma unroll
      for (int e = 0; e < 8; ++e) cv[e] = f2bf(cur[e]);
      *(ushortx8*)&pp[cb][pw4][pc8] = cv;
      if (x1 > 0){
        const ushortx8 pv = *(const ushortx8*)&pp[pbuf][pw4][pc8];
        ushortx8 av;
#pragma unroll
        for (int e = 0; e < 8; ++e) av[e] = f2bf((cur[e] + bf2f(pv[e])) * 0.5f);
        *(ushortx8*)&Ab[pw4 * 136 + pc8] = av;
      }
    }
    __syncthreads();   // Ab ready (S consumed)

    if (x1 > 0){
      // ---- MFMA: wave w -> col tiles {2w, 2w+1} ----
      floatx4 acc[2];
      acc[0] = (floatx4){0.f,0.f,0.f,0.f};
      acc[1] = (floatx4){0.f,0.f,0.f,0.f};
#pragma unroll
      for (int s4 = 0; s4 < 4; ++s4){
        const bf16x8 af = *(const bf16x8*)&Ab[l16 * 136 + s4 * 32 + quad * 8];
#pragma unroll
        for (int cc = 0; cc < 2; ++cc){
          const bf16x8 bv = *(const bf16x8*)&Mb[(wave * 2 + cc) * 16 + l16][s4 * 32 + quad * 8];
          acc[cc] = __builtin_amdgcn_mfma_f32_16x16x32_bf16(af, bv, acc[cc], 0, 0, 0);
        }
      }
      // ---- Ct (aliases S) + Nk stage ----
      float* Ct = S;
#pragma unroll
      for (int cc = 0; cc < 2; ++cc)
#pragma unroll
        for (int reg = 0; reg < 4; ++reg)
          Ct[(quad * 4 + reg) * 132 + (wave * 2 + cc) * 16 + l16] = acc[cc][reg];

      const int j1 = (x1 - 1) & 3;
      const int idxBase = ((j1 * 4 + (w2 & 3)) * 4 + (w3 & 3)) * 4;
#pragma unroll
      for (int k = 0; k < 2; ++k){
        const int e = k * 256 + t;
        sNkStep[e] = NkFull[(idxBase + (e >> 7)) * 128 + (e & 127)];
      }
      __syncthreads();   // Ct + Nk ready

      // ---- coalesced stores: 15 rows x 512 B contiguous ----
      const size_t outBase = ((size_t)(((b * 15 + (x1 - 1)) * 15 + w2) * 15 + w3)) * 15;
#pragma unroll
      for (int k = 0; k < 2; ++k){
        const int ci = k * 256 + t;
        if (ci < 480){
          const int row = ci >> 5, c4 = (ci & 31) * 4;
          const floatx4 v  = *(const floatx4*)&Ct[row * 132 + c4];
          const floatx4 nk = *(const floatx4*)&sNkStep[(row & 3) * 128 + c4];
          floatx4 o;
#pragma unroll
          for (int e = 0; e < 4; ++e) o[e] = nk[e] - v[e];
          if (isf){
            *(floatx4*)((float*)out + (outBase + row) * 128 + c4) = o;
          } else {
            ushortx4 ob;
#pragma unroll
            for (int e = 0; e < 4; ++e) ob[e] = f2bf(o[e]);
            *(ushortx4*)((unsigned short*)out + (outBase + row) * 128 + c4) = ob;
          }
        }
      }
    }
  }
}

extern "C" void kernel_launch(void* const* d_in, const int* in_sizes, int n_in,
                              void* d_out, int out_size, void* d_ws, size_t ws_size,
                              hipStream_t stream) {
  const void* vec = d_in[0];   // (4,16,16,16,16,128)
  const void* Mm  = d_in[1];   // (128,128)
  const void* Ac  = d_in[2];   // (128,256)
  const void* Bb  = d_in[3];   // (256,128)

  float* NkFull = (float*)d_ws;
  unsigned short* Mbf = (unsigned short*)((char*)d_ws + MBF_OFF);

  nk2_kernel<<<192, 256, 0, stream>>>(Ac, Bb, Mm, NkFull, Mbf);
  mega_kernel<<<904, 256, 0, stream>>>(vec, NkFull, Mbf, Bb, d_out);
}